// Round 1
// baseline (456.293 us; speedup 1.0000x reference)
//
#include <hip/hip_runtime.h>
#include <hip/hip_fp16.h>

#define N_ 4
#define H_ 256
#define W_ 256
#define C_ 96
#define CH 48      // channels per block (half of C_)
#define NC4 12     // CH/4
#define PAD 257    // padded LDS row length (floats)
#define NFILT 4

__constant__ float c_a[NFILT] = {0.1f, 0.3f, 0.4f, 0.8f};

// Forward scan along 256 positions distributed as lane*4+j.
// Recurrence: y_p = (1-a)*x_p + a*y_{p-1}, init carry y_{-1} := x_0 (=> y_0 = x_0).
__device__ __forceinline__ void scan_fwd(float &v0, float &v1, float &v2, float &v3,
                                         float a, int lane) {
  const float b = 1.0f - a;
  const float a2 = a * a, a3 = a2 * a, a4 = a2 * a2;
  float t0 = b * v0;
  float t1 = fmaf(a, t0, b * v1);
  float t2 = fmaf(a, t1, b * v2);
  float t3 = fmaf(a, t2, b * v3);
  if (lane == 0) {  // fold init carry x_0 (lane0's v0)
    t0 = fmaf(a,  v0, t0);
    t1 = fmaf(a2, v0, t1);
    t2 = fmaf(a3, v0, t2);
    t3 = fmaf(a4, v0, t3);
  }
  float c = t3;   // lane's end value with zero carry-in
  float m = a4;   // A^d, A = a^4
  #pragma unroll
  for (int d = 1; d < 64; d <<= 1) {
    float o = __shfl_up(c, (unsigned)d, 64);
    if (lane >= d) c = fmaf(m, o, c);
    m = m * m;
  }
  float cin = __shfl_up(c, 1u, 64);
  if (lane == 0) cin = 0.0f;
  v0 = fmaf(a,  cin, t0);
  v1 = fmaf(a2, cin, t1);
  v2 = fmaf(a3, cin, t2);
  v3 = fmaf(a4, cin, t3);
}

// Anticausal: out_p = (1-a)*y_p + a*out_{p+1}, init carry out_{256} := y_255.
__device__ __forceinline__ void scan_bwd(float &v0, float &v1, float &v2, float &v3,
                                         float a, int lane) {
  const float b = 1.0f - a;
  const float a2 = a * a, a3 = a2 * a, a4 = a2 * a2;
  float t3 = b * v3;
  float t2 = fmaf(a, t3, b * v2);
  float t1 = fmaf(a, t2, b * v1);
  float t0 = fmaf(a, t1, b * v0);
  if (lane == 63) {  // fold init carry y_255 (lane63's v3)
    t3 = fmaf(a,  v3, t3);
    t2 = fmaf(a2, v3, t2);
    t1 = fmaf(a3, v3, t1);
    t0 = fmaf(a4, v3, t0);
  }
  float c = t0;
  float m = a4;
  #pragma unroll
  for (int d = 1; d < 64; d <<= 1) {
    float o = __shfl_down(c, (unsigned)d, 64);
    if (lane < 64 - d) c = fmaf(m, o, c);
    m = m * m;
  }
  float cin = __shfl_down(c, 1u, 64);
  if (lane == 63) cin = 0.0f;
  v3 = fmaf(a,  cin, t3);
  v2 = fmaf(a2, cin, t2);
  v1 = fmaf(a3, cin, t1);
  v0 = fmaf(a4, cin, t0);
}

// Kernel 1: W-axis fwd+bwd IIR. One block = one (n,h) row, one 48-channel half,
// one filter. Writes fp16 intermediate inter[fi][n][h][w][c].
__global__ __launch_bounds__(256)
void k_wpass(const float* __restrict__ x, __half* __restrict__ inter,
             int f_start, int nf) {
  __shared__ float lds[CH * PAD];
  const int fi    = blockIdx.x % nf;
  const int chalf = blockIdx.x / nf;
  const int row   = blockIdx.y;          // n*H_ + h
  const int c0    = chalf * CH;
  const float a   = c_a[f_start + fi];
  const int t     = threadIdx.x;

  const float* xrow = x + (size_t)row * (W_ * C_) + c0;
  #pragma unroll
  for (int i = 0; i < 12; ++i) {         // 256 w * 12 float4-groups / 256 thr
    int idx = t + i * 256;
    int w = idx / NC4, c4 = idx % NC4;
    const float4 v = *(const float4*)(xrow + (size_t)w * C_ + 4 * c4);
    lds[(4 * c4 + 0) * PAD + w] = v.x;
    lds[(4 * c4 + 1) * PAD + w] = v.y;
    lds[(4 * c4 + 2) * PAD + w] = v.z;
    lds[(4 * c4 + 3) * PAD + w] = v.w;
  }
  __syncthreads();
  const int wave = t >> 6, lane = t & 63;
  #pragma unroll
  for (int ci = 0; ci < NC4; ++ci) {
    float* r = lds + (wave + 4 * ci) * PAD + 4 * lane;
    float v0 = r[0], v1 = r[1], v2 = r[2], v3 = r[3];
    scan_fwd(v0, v1, v2, v3, a, lane);
    scan_bwd(v0, v1, v2, v3, a, lane);
    r[0] = v0; r[1] = v1; r[2] = v2; r[3] = v3;
  }
  __syncthreads();
  __half* irow = inter + ((size_t)fi * (N_ * H_) + row) * (W_ * C_) + c0;
  #pragma unroll
  for (int i = 0; i < 12; ++i) {
    int idx = t + i * 256;
    int w = idx / NC4, c4 = idx % NC4;
    union { uint2 u; __half2 h2[2]; } pk;
    pk.h2[0] = __floats2half2_rn(lds[(4 * c4 + 0) * PAD + w],
                                 lds[(4 * c4 + 1) * PAD + w]);
    pk.h2[1] = __floats2half2_rn(lds[(4 * c4 + 2) * PAD + w],
                                 lds[(4 * c4 + 3) * PAD + w]);
    *(uint2*)(irow + (size_t)w * C_ + 4 * c4) = pk.u;
  }
}

// Kernel 2: H-axis fwd+bwd IIR per filter + softmax-weighted accumulation.
// One block = one (n,w) column, one 48-channel half; loops nf filters.
__global__ __launch_bounds__(256)
void k_hpass(const __half* __restrict__ inter, const float* __restrict__ gate,
             float* __restrict__ out, int f_start, int nf, int accumulate) {
  __shared__ float lds[CH * PAD];
  __shared__ float wlds[NFILT * CH];
  const int chalf = blockIdx.x;
  const int col   = blockIdx.y;          // n*W_ + w
  const int n = col / W_, w = col % W_;
  const int c0 = chalf * CH;
  const int t = threadIdx.x;
  const int wave = t >> 6, lane = t & 63;

  if (t < CH) {  // softmax over the 4 gate logits, per channel
    const int c = c0 + t;
    float g0 = gate[0 * C_ + c], g1 = gate[1 * C_ + c];
    float g2 = gate[2 * C_ + c], g3 = gate[3 * C_ + c];
    float mx = fmaxf(fmaxf(g0, g1), fmaxf(g2, g3));
    float e0 = __expf(g0 - mx), e1 = __expf(g1 - mx);
    float e2 = __expf(g2 - mx), e3 = __expf(g3 - mx);
    float inv = 1.0f / (e0 + e1 + e2 + e3);
    wlds[0 * CH + t] = e0 * inv;
    wlds[1 * CH + t] = e1 * inv;
    wlds[2 * CH + t] = e2 * inv;
    wlds[3 * CH + t] = e3 * inv;
  }

  float acc[NC4][4];
  #pragma unroll
  for (int ci = 0; ci < NC4; ++ci)
    acc[ci][0] = acc[ci][1] = acc[ci][2] = acc[ci][3] = 0.0f;

  for (int fi = 0; fi < nf; ++fi) {
    const int f = f_start + fi;
    const float a = c_a[f];
    __syncthreads();  // previous tile fully consumed (and wlds ready)
    const __half* icol = inter + (size_t)fi * ((size_t)N_ * H_ * W_ * C_)
                       + ((size_t)n * H_ * W_ + w) * C_ + c0;
    #pragma unroll
    for (int i = 0; i < 12; ++i) {
      int idx = t + i * 256;
      int h = idx / NC4, c4 = idx % NC4;
      union { uint2 u; __half2 h2[2]; } pk;
      pk.u = *(const uint2*)(icol + (size_t)h * (W_ * C_) + 4 * c4);
      float2 f01 = __half22float2(pk.h2[0]);
      float2 f23 = __half22float2(pk.h2[1]);
      lds[(4 * c4 + 0) * PAD + h] = f01.x;
      lds[(4 * c4 + 1) * PAD + h] = f01.y;
      lds[(4 * c4 + 2) * PAD + h] = f23.x;
      lds[(4 * c4 + 3) * PAD + h] = f23.y;
    }
    __syncthreads();
    #pragma unroll
    for (int ci = 0; ci < NC4; ++ci) {
      const int c = wave + 4 * ci;
      float* r = lds + c * PAD + 4 * lane;
      float v0 = r[0], v1 = r[1], v2 = r[2], v3 = r[3];
      scan_fwd(v0, v1, v2, v3, a, lane);
      scan_bwd(v0, v1, v2, v3, a, lane);
      const float wg = wlds[f * CH + c];
      acc[ci][0] = fmaf(wg, v0, acc[ci][0]);
      acc[ci][1] = fmaf(wg, v1, acc[ci][1]);
      acc[ci][2] = fmaf(wg, v2, acc[ci][2]);
      acc[ci][3] = fmaf(wg, v3, acc[ci][3]);
    }
  }
  __syncthreads();
  #pragma unroll
  for (int ci = 0; ci < NC4; ++ci) {
    float* r = lds + (wave + 4 * ci) * PAD + 4 * lane;
    r[0] = acc[ci][0]; r[1] = acc[ci][1]; r[2] = acc[ci][2]; r[3] = acc[ci][3];
  }
  __syncthreads();
  float* ocol = out + ((size_t)n * H_ * W_ + w) * C_ + c0;
  #pragma unroll
  for (int i = 0; i < 12; ++i) {
    int idx = t + i * 256;
    int h = idx / NC4, c4 = idx % NC4;
    float4 v;
    v.x = lds[(4 * c4 + 0) * PAD + h];
    v.y = lds[(4 * c4 + 1) * PAD + h];
    v.z = lds[(4 * c4 + 2) * PAD + h];
    v.w = lds[(4 * c4 + 3) * PAD + h];
    float4* dst = (float4*)(ocol + (size_t)h * (W_ * C_) + 4 * c4);
    if (accumulate) {
      float4 p = *dst;
      v.x += p.x; v.y += p.y; v.z += p.z; v.w += p.w;
    }
    *dst = v;
  }
}

extern "C" void kernel_launch(void* const* d_in, const int* in_sizes, int n_in,
                              void* d_out, int out_size, void* d_ws, size_t ws_size,
                              hipStream_t stream) {
  const float* x    = (const float*)d_in[0];
  const float* gate = (const float*)d_in[1];
  float* out        = (float*)d_out;
  __half* inter     = (__half*)d_ws;

  const size_t per_f = (size_t)N_ * H_ * W_ * C_ * sizeof(__half);  // 50.3 MB
  int batch = 1;
  if (ws_size >= 4 * per_f)      batch = 4;
  else if (ws_size >= 2 * per_f) batch = 2;

  int done = 0;
  while (done < NFILT) {
    int nf = NFILT - done;
    if (nf > batch) nf = batch;
    dim3 g1(2 * nf, N_ * H_);
    k_wpass<<<g1, dim3(256), 0, stream>>>(x, inter, done, nf);
    dim3 g2(2, N_ * W_);
    k_hpass<<<g2, dim3(256), 0, stream>>>(inter, gate, out, done, nf,
                                          done > 0 ? 1 : 0);
    done += nf;
  }
}

// Round 2
// 341.212 us; speedup vs baseline: 1.3373x; 1.3373x over previous
//
#include <hip/hip_runtime.h>
#include <hip/hip_fp16.h>

#define N_ 4
#define H_ 256
#define W_ 256
#define C_ 96
#define CH 48      // channels per block (half of C_)
#define NC4 12     // CH/4
#define TP 258     // tile row stride (halves)
#define SP 132     // stage row stride (floats)
#define NFILT 4

__constant__ float c_a[NFILT] = {0.1f, 0.3f, 0.4f, 0.8f};

// Forward scan, 256 positions as lane*4+j. Truncated Kogge-Stone: carry
// multiplier A=a^4<=0.41; omitted terms weigh A^16~6e-7 -> steps {1,2,4,8}.
__device__ __forceinline__ void scan_fwd(float &v0, float &v1, float &v2, float &v3,
                                         float a, int lane) {
  const float b = 1.0f - a;
  const float a2 = a * a, a3 = a2 * a, a4 = a2 * a2;
  float t0 = b * v0;
  float t1 = fmaf(a, t0, b * v1);
  float t2 = fmaf(a, t1, b * v2);
  float t3 = fmaf(a, t2, b * v3);
  if (lane == 0) {  // init carry y_{-1} := x_0  => y_0 = x_0
    t0 = fmaf(a,  v0, t0);
    t1 = fmaf(a2, v0, t1);
    t2 = fmaf(a3, v0, t2);
    t3 = fmaf(a4, v0, t3);
  }
  float c = t3;
  float m = a4;
  #pragma unroll
  for (int d = 1; d <= 8; d <<= 1) {
    float o = __shfl_up(c, (unsigned)d, 64);
    if (lane >= d) c = fmaf(m, o, c);
    m = m * m;
  }
  float cin = __shfl_up(c, 1u, 64);
  if (lane == 0) cin = 0.0f;
  v0 = fmaf(a,  cin, t0);
  v1 = fmaf(a2, cin, t1);
  v2 = fmaf(a3, cin, t2);
  v3 = fmaf(a4, cin, t3);
}

__device__ __forceinline__ void scan_bwd(float &v0, float &v1, float &v2, float &v3,
                                         float a, int lane) {
  const float b = 1.0f - a;
  const float a2 = a * a, a3 = a2 * a, a4 = a2 * a2;
  float t3 = b * v3;
  float t2 = fmaf(a, t3, b * v2);
  float t1 = fmaf(a, t2, b * v1);
  float t0 = fmaf(a, t1, b * v0);
  if (lane == 63) {  // init carry := y_255
    t3 = fmaf(a,  v3, t3);
    t2 = fmaf(a2, v3, t2);
    t1 = fmaf(a3, v3, t1);
    t0 = fmaf(a4, v3, t0);
  }
  float c = t0;
  float m = a4;
  #pragma unroll
  for (int d = 1; d <= 8; d <<= 1) {
    float o = __shfl_down(c, (unsigned)d, 64);
    if (lane < 64 - d) c = fmaf(m, o, c);
    m = m * m;
  }
  float cin = __shfl_down(c, 1u, 64);
  if (lane == 63) cin = 0.0f;
  v3 = fmaf(a,  cin, t3);
  v2 = fmaf(a2, cin, t2);
  v1 = fmaf(a3, cin, t1);
  v0 = fmaf(a4, cin, t0);
}

// W-pass: block = (fi, chalf) x (n*H+h). Coalesced x read -> fp16 LDS tile
// [c][w] -> in-register scan (in-place writeback) -> scatter-store 96B/w
// segments to transposed inter[fi][chalf][n][w][h][c48] (h-adjacent blocks
// merge segments into full lines in L2).
__global__ __launch_bounds__(256, 4)
void k_wpass(const float* __restrict__ x, __half* __restrict__ inter,
             int f_start, int nf) {
  __shared__ __half tile[CH * TP];
  const int chalf = blockIdx.x & 1;
  const int fi    = blockIdx.x >> 1;
  const int row   = blockIdx.y;          // n*H_ + h
  const int h     = row & 255;
  const int c0    = chalf * CH;
  const float a   = c_a[f_start + fi];
  const int t     = threadIdx.x;
  const int wave  = t >> 6, lane = t & 63;

  const float* xrow = x + (size_t)row * (W_ * C_) + c0;
  #pragma unroll
  for (int i = 0; i < 12; ++i) {
    int idx = t + i * 256;
    int w = idx / NC4, c4 = idx % NC4;
    const float4 v = *(const float4*)(xrow + (size_t)w * C_ + 4 * c4);
    tile[(4 * c4 + 0) * TP + w] = __float2half(v.x);
    tile[(4 * c4 + 1) * TP + w] = __float2half(v.y);
    tile[(4 * c4 + 2) * TP + w] = __float2half(v.z);
    tile[(4 * c4 + 3) * TP + w] = __float2half(v.w);
  }
  __syncthreads();
  #pragma unroll
  for (int ci = 0; ci < NC4; ++ci) {
    const int c = wave + 4 * ci;
    __half2* p = (__half2*)(tile + c * TP + 4 * lane);
    float2 f01 = __half22float2(p[0]);
    float2 f23 = __half22float2(p[1]);
    float v0 = f01.x, v1 = f01.y, v2 = f23.x, v3 = f23.y;
    scan_fwd(v0, v1, v2, v3, a, lane);
    scan_bwd(v0, v1, v2, v3, a, lane);
    p[0] = __floats2half2_rn(v0, v1);
    p[1] = __floats2half2_rn(v2, v3);
  }
  __syncthreads();
  // inter[((fi*2+chalf)*N + n)*W + w] is a contiguous H*CH-halves chunk.
  __half* ibase = inter + (((size_t)(fi * 2 + chalf) * N_ * W_ + (size_t)(row >> 8) * W_)
                           * (H_ * CH)) + (size_t)h * CH;
  #pragma unroll
  for (int i = 0; i < 6; ++i) {
    int idx = t + i * 256;               // 1536 uint4s
    int w = idx / 6, j = idx % 6;
    union { uint4 u; ushort s[8]; } pk;
    #pragma unroll
    for (int k = 0; k < 8; ++k)
      pk.s[k] = __half_as_ushort(tile[(8 * j + k) * TP + w]);
    *(uint4*)(ibase + (size_t)w * (H_ * CH) + 8 * j) = pk.u;
  }
}

// H-pass: block = (chalf) x (n*W+w). Per filter: fully-contiguous 24KB chunk
// -> 6 uint4 regs (prefetched across filters) -> LDS transpose [c][h] ->
// scan + weighted accumulate in regs -> staged coalesced out writes.
__global__ __launch_bounds__(256, 4)
void k_hpass(const __half* __restrict__ inter, const float* __restrict__ gate,
             float* __restrict__ out, int f_start, int nf, int accumulate) {
  __shared__ __align__(16) unsigned char smem[CH * SP * 4];  // 25344 B
  __half* tile = (__half*)smem;        // CH*TP*2 = 24768 B
  float*  stage = (float*)smem;        // CH*SP*4 (after scans)
  __shared__ float wlds[NFILT * CH];
  const int chalf = blockIdx.x;
  const int col   = blockIdx.y;        // n*W_ + w
  const int n = col >> 8, w = col & 255;
  const int c0 = chalf * CH;
  const int t = threadIdx.x;
  const int wave = t >> 6, lane = t & 63;

  if (t < CH) {
    const int c = c0 + t;
    float g0 = gate[0 * C_ + c], g1 = gate[1 * C_ + c];
    float g2 = gate[2 * C_ + c], g3 = gate[3 * C_ + c];
    float mx = fmaxf(fmaxf(g0, g1), fmaxf(g2, g3));
    float e0 = __expf(g0 - mx), e1 = __expf(g1 - mx);
    float e2 = __expf(g2 - mx), e3 = __expf(g3 - mx);
    float inv = 1.0f / (e0 + e1 + e2 + e3);
    wlds[0 * CH + t] = e0 * inv;
    wlds[1 * CH + t] = e1 * inv;
    wlds[2 * CH + t] = e2 * inv;
    wlds[3 * CH + t] = e3 * inv;
  }

  float acc[NC4][4];
  #pragma unroll
  for (int ci = 0; ci < NC4; ++ci)
    acc[ci][0] = acc[ci][1] = acc[ci][2] = acc[ci][3] = 0.0f;

  const size_t chunk = (size_t)H_ * CH;  // halves per (fi,chalf,n,w) chunk
  uint4 pf[6];
  {
    const uint4* src = (const uint4*)(inter +
        ((size_t)(0 * 2 + chalf) * N_ * W_ + (size_t)n * W_ + w) * chunk);
    #pragma unroll
    for (int i = 0; i < 6; ++i) pf[i] = src[i * 256 + t];
  }

  for (int fi = 0; fi < nf; ++fi) {
    __syncthreads();                     // prev scan reads done (and wlds ready)
    #pragma unroll
    for (int i = 0; i < 6; ++i) {
      int e = i * 256 + t;
      int h = e / 6, c8 = e % 6;
      union { uint4 u; ushort s[8]; } pk;
      pk.u = pf[i];
      #pragma unroll
      for (int k = 0; k < 8; ++k)
        tile[(8 * c8 + k) * TP + h] = __ushort_as_half(pk.s[k]);
    }
    __syncthreads();
    if (fi + 1 < nf) {                   // prefetch next filter's chunk
      const uint4* src = (const uint4*)(inter +
          ((size_t)((fi + 1) * 2 + chalf) * N_ * W_ + (size_t)n * W_ + w) * chunk);
      #pragma unroll
      for (int i = 0; i < 6; ++i) pf[i] = src[i * 256 + t];
    }
    const float a = c_a[f_start + fi];
    #pragma unroll
    for (int ci = 0; ci < NC4; ++ci) {
      const int c = wave + 4 * ci;
      const __half2* p = (const __half2*)(tile + c * TP + 4 * lane);
      float2 f01 = __half22float2(p[0]);
      float2 f23 = __half22float2(p[1]);
      float v0 = f01.x, v1 = f01.y, v2 = f23.x, v3 = f23.y;
      scan_fwd(v0, v1, v2, v3, a, lane);
      scan_bwd(v0, v1, v2, v3, a, lane);
      const float wg = wlds[(f_start + fi) * CH + c];
      acc[ci][0] = fmaf(wg, v0, acc[ci][0]);
      acc[ci][1] = fmaf(wg, v1, acc[ci][1]);
      acc[ci][2] = fmaf(wg, v2, acc[ci][2]);
      acc[ci][3] = fmaf(wg, v3, acc[ci][3]);
    }
  }

  // Output: two half-h rounds through a 25KB fp32 stage (reuses tile LDS).
  #pragma unroll
  for (int r = 0; r < 2; ++r) {
    __syncthreads();
    if ((lane >> 5) == r) {
      const int hl = 4 * (lane & 31);
      #pragma unroll
      for (int ci = 0; ci < NC4; ++ci) {
        float4* sp = (float4*)(stage + (wave + 4 * ci) * SP + hl);
        *sp = make_float4(acc[ci][0], acc[ci][1], acc[ci][2], acc[ci][3]);
      }
    }
    __syncthreads();
    float* obase = out + (((size_t)n * H_ + 128 * r) * W_ + w) * C_ + c0;
    #pragma unroll
    for (int i = 0; i < 6; ++i) {
      int idx = t + i * 256;
      int hl = idx / NC4, c4 = idx % NC4;
      float4 v;
      v.x = stage[(4 * c4 + 0) * SP + hl];
      v.y = stage[(4 * c4 + 1) * SP + hl];
      v.z = stage[(4 * c4 + 2) * SP + hl];
      v.w = stage[(4 * c4 + 3) * SP + hl];
      float4* dst = (float4*)(obase + (size_t)hl * (W_ * C_) + 4 * c4);
      if (accumulate) {
        float4 pv = *dst;
        v.x += pv.x; v.y += pv.y; v.z += pv.z; v.w += pv.w;
      }
      *dst = v;
    }
  }
}

extern "C" void kernel_launch(void* const* d_in, const int* in_sizes, int n_in,
                              void* d_out, int out_size, void* d_ws, size_t ws_size,
                              hipStream_t stream) {
  const float* x    = (const float*)d_in[0];
  const float* gate = (const float*)d_in[1];
  float* out        = (float*)d_out;
  __half* inter     = (__half*)d_ws;

  const size_t per_f = (size_t)N_ * H_ * W_ * C_ * sizeof(__half);  // 50.3 MB
  int batch = 1;
  if (ws_size >= 4 * per_f)      batch = 4;
  else if (ws_size >= 2 * per_f) batch = 2;

  int done = 0;
  while (done < NFILT) {
    int nf = NFILT - done;
    if (nf > batch) nf = batch;
    dim3 g1(2 * nf, N_ * H_);
    k_wpass<<<g1, dim3(256), 0, stream>>>(x, inter, done, nf);
    dim3 g2(2, N_ * W_);
    k_hpass<<<g2, dim3(256), 0, stream>>>(inter, gate, out, done, nf,
                                          done > 0 ? 1 : 0);
    done += nf;
  }
}